// Round 10
// baseline (613.065 us; speedup 1.0000x reference)
//
#include <hip/hip_runtime.h>
#include <math.h>

#define D 128
#define GCN_NUM 3
#define HEADS 8
#define HD 16
#define L_SEQ 100
#define LEAKY 0.01f
#define SC_BUCKETS 8

typedef __attribute__((ext_vector_type(8))) short short8v;
typedef __attribute__((ext_vector_type(4))) float f32x4;

__device__ __forceinline__ unsigned f2bf(float x) {
  unsigned u = __float_as_uint(x);
  return (u + 0x7FFFu + ((u >> 16) & 1u)) >> 16;
}
__device__ __forceinline__ float bflo2f(unsigned u) { return __uint_as_float(u << 16); }
__device__ __forceinline__ float bfhi2f(unsigned u) { return __uint_as_float(u & 0xFFFF0000u); }

// ---------------- prep: converts (embeds -> slice-major bf16; weights linear) + inits ----------------

__global__ void prep(const float* __restrict__ s0, unsigned short* __restrict__ d0, int n0,
                     const float* __restrict__ s1, unsigned short* __restrict__ d1, int n1,
                     const float* __restrict__ s2, unsigned short* __restrict__ d2, int n2,
                     int* __restrict__ deg, int N, int* __restrict__ ctr, size_t strideS) {
  int i = blockIdx.x * blockDim.x + threadIdx.x;
  int n4tot = n0 + n1 + n2;
  if (i < n0) {
    // embeds: slice-major destination [8][Npad][16]
    float4 v = reinterpret_cast<const float4*>(s0)[i];
    int row = i >> 5;          // D/4 = 32 float4 per row
    int k = (i & 31) * 4;      // feature index of v.x
    uint2 o;
    o.x = f2bf(v.x) | (f2bf(v.y) << 16);
    o.y = f2bf(v.z) | (f2bf(v.w) << 16);
    unsigned short* dst = d0 + (size_t)(k >> 4) * strideS + (size_t)row * 16 + (k & 15);
    *reinterpret_cast<uint2*>(dst) = o;
  } else if (i < n4tot) {
    const float* s; unsigned short* d; int j;
    if (i < n0 + n1) { s = s1; d = d1; j = i - n0; }
    else             { s = s2; d = d2; j = i - n0 - n1; }
    float4 v = reinterpret_cast<const float4*>(s)[j];
    uint2 o;
    o.x = f2bf(v.x) | (f2bf(v.y) << 16);
    o.y = f2bf(v.z) | (f2bf(v.w) << 16);
    reinterpret_cast<uint2*>(d)[j] = o;
  } else if (i - n4tot < N) {
    deg[i - n4tot] = 1;  // self-loop
  }
  if (i < GCN_NUM * 8) ctr[i] = 0;  // spmm slice work-queues
}

// ---------------- graph build ----------------

__global__ void count_deg(const int* __restrict__ e0, const int* __restrict__ e1,
                          int* __restrict__ deg, int E) {
  int stride = gridDim.x * blockDim.x;
  for (int i = blockIdx.x * blockDim.x + threadIdx.x; i < E; i += stride) {
    atomicAdd(&deg[e0[i]], 1);
    atomicAdd(&deg[e1[i]], 1);
  }
}

__global__ __launch_bounds__(1024) void block_sum(const int* __restrict__ deg,
                                                  int* __restrict__ bsum, int n) {
  __shared__ int ws[16];
  int tid = threadIdx.x, lane = tid & 63, wid = tid >> 6;
  int i = blockIdx.x * 1024 + tid;
  int v = (i < n) ? deg[i] : 0;
#pragma unroll
  for (int off = 32; off; off >>= 1) v += __shfl_xor(v, off);
  if (lane == 0) ws[wid] = v;
  __syncthreads();
  if (tid == 0) {
    int s = 0;
#pragma unroll
    for (int k = 0; k < 16; ++k) s += ws[k];
    bsum[blockIdx.x] = s;
  }
}

__global__ __launch_bounds__(1024) void scan_final(
    const int* __restrict__ deg, const int* __restrict__ bsum,
    int* __restrict__ row_ptr, int* __restrict__ cursor, int n, int nb) {
  __shared__ int ws[16];
  __shared__ int prefix_s;
  int tid = threadIdx.x, lane = tid & 63, wid = tid >> 6;
  int i = blockIdx.x * 1024 + tid;
  int v = (i < n) ? deg[i] : 0;
  int x = v;
#pragma unroll
  for (int off = 1; off < 64; off <<= 1) {
    int y = __shfl_up(x, off);
    if (lane >= off) x += y;
  }
  if (lane == 63) ws[wid] = x;
  __syncthreads();
  if (wid == 0) {
    int pv = (lane < blockIdx.x) ? bsum[lane] : 0;
#pragma unroll
    for (int off = 32; off; off >>= 1) pv += __shfl_xor(pv, off);
    if (lane == 0) prefix_s = pv;
    int s = (lane < 16) ? ws[lane] : 0;
#pragma unroll
    for (int off = 1; off < 16; off <<= 1) {
      int y = __shfl_up(s, off);
      if (lane >= off) s += y;
    }
    if (lane < 16) ws[lane] = s;
  }
  __syncthreads();
  int woff = wid ? ws[wid - 1] : 0;
  int prefix = prefix_s;
  if (i < n) {
    int pval = prefix + woff + (x - v);
    row_ptr[i] = pval;
    cursor[i] = pval;
  }
  if (blockIdx.x == nb - 1 && tid == 0) row_ptr[n] = prefix + ws[15];
}

// bucketed scatter, 4-byte packed descriptor (col u16 | bf16 w << 16)
__global__ __launch_bounds__(256) void scatter_edges_p(
    const int* __restrict__ e0, const int* __restrict__ e1,
    const float* __restrict__ dv, const int* __restrict__ deg,
    int* __restrict__ cursor, unsigned* __restrict__ ecw,
    int E, int N, int span, int bpb) {
  int bucket = blockIdx.x & (SC_BUCKETS - 1);
  int bx = blockIdx.x >> 3;
  int rlo = bucket * span;
  int rhi = min(rlo + span, N);
  int total = 2 * E + N;
  int stride = bpb * 256;
  for (int i = bx * 256 + threadIdx.x; i < total; i += stride) {
    int r, c; bool self = false;
    if (i < E)          { r = e0[i];     c = e1[i]; }
    else if (i < 2 * E) { r = e1[i - E]; c = e0[i - E]; }
    else                { r = i - 2 * E; c = r; self = true; }
    if (r < rlo || r >= rhi) continue;
    float d = self ? 0.f : dv[(i < E) ? i : i - E];
    float w = expf(-d * d) * (1.0f / sqrtf((float)deg[r])) * (1.0f / sqrtf((float)deg[c]));
    int pos = atomicAdd(&cursor[r], 1);
    ecw[pos] = (unsigned)c | (f2bf(w) << 16);
  }
}

// ---------------- GCN ----------------

// Slice-local SpMM: slice = physical XCC_ID; per-slice working set = 1.6MB (fits 4MB L2).
// Block = 16 groups x 16 lanes; group handles one row; subgroups of 8 lanes = 2 edges in flight.
// Work claimed in 64-row chunks from a per-slice atomic queue.
__global__ __launch_bounds__(256) void spmm_slice(
    const int* __restrict__ row_ptr, const unsigned* __restrict__ ecw,
    const unsigned short* __restrict__ in_s, unsigned short* __restrict__ out_s,
    int* __restrict__ ctr, int n, size_t strideS) {
  unsigned xcc;
  asm volatile("s_getreg_b32 %0, hwreg(HW_REG_XCC_ID)" : "=s"(xcc));
  int slice = (int)(xcc & 7u);
  const unsigned short* in = in_s + (size_t)slice * strideS;
  unsigned short* out = out_s + (size_t)slice * strideS;
  int tid = threadIdx.x;
  int grp = tid >> 4;        // 16 groups
  int sub = (tid >> 3) & 1;  // 2 edge-subgroups per group
  int fl = tid & 7;          // feature lane: features 2*fl, 2*fl+1
  int nch = (n + 63) >> 6;
  __shared__ int chunk_s;
  for (;;) {
    __syncthreads();
    if (tid == 0) chunk_s = atomicAdd(&ctr[slice], 1);
    __syncthreads();
    int ch = chunk_s;
    if (ch >= nch) break;
    int rbase = ch << 6;
#pragma unroll
    for (int ps = 0; ps < 4; ++ps) {
      int r = rbase + ps * 16 + grp;
      if (r >= n) continue;
      int sE = row_ptr[r], eE = row_ptr[r + 1];
      float acc0 = 0.f, acc1 = 0.f;
      int i = sE + sub;
      unsigned dA = (i < eE) ? ecw[i] : 0u;          // desc 0 => w = 0 (harmless gather of row 0)
      unsigned dB = (i + 2 < eE) ? ecw[i + 2] : 0u;
      while (i < eE) {
        unsigned dn = (i + 4 < eE) ? ecw[i + 4] : 0u;
        float w = bfhi2f(dA);
        unsigned u = *reinterpret_cast<const unsigned*>(in + (size_t)(dA & 0xFFFFu) * 16 + fl * 2);
        acc0 = fmaf(w, bflo2f(u), acc0);
        acc1 = fmaf(w, bfhi2f(u), acc1);
        dA = dB; dB = dn; i += 2;
      }
      acc0 += __shfl_xor(acc0, 8);
      acc1 += __shfl_xor(acc1, 8);
      if (sub == 0) {
        unsigned o = f2bf(acc0) | (f2bf(acc1) << 16);
        *reinterpret_cast<unsigned*>(out + (size_t)r * 16 + fl * 2) = o;
      }
    }
  }
}

// enc = normalize(leaky_relu(A @ W^T + b)) via MFMA bf16; A and enc are slice-major.
__global__ __launch_bounds__(256) void dense_mfma(
    const unsigned short* __restrict__ A, const unsigned short* __restrict__ Wb,
    const float* __restrict__ bias, unsigned short* __restrict__ enc,
    int n, size_t strideS) {
  __shared__ unsigned short Wl[128 * 136];
  int tid = threadIdx.x;
  {
    int cg = (tid & 15) * 8;
    int r0 = tid >> 4;
#pragma unroll
    for (int i = 0; i < 8; ++i) {
      int row = r0 + i * 16;
      *reinterpret_cast<short8v*>(&Wl[row * 136 + cg]) =
          *reinterpret_cast<const short8v*>(Wb + row * D + cg);
    }
  }
  __syncthreads();
  int w = tid >> 6, lane = tid & 63;
  int lr = lane & 15, lg = lane >> 4;
#pragma unroll
  for (int rt = 0; rt < 2; ++rt) {
    int rbase = blockIdx.x * 128 + rt * 64 + w * 16;
    f32x4 acc[8];
#pragma unroll
    for (int j = 0; j < 8; ++j) acc[j] = f32x4{0.f, 0.f, 0.f, 0.f};
    // A fragment: k = ks*32 + lg*8 -> slice 2*ks + (lg>>1), offset 8*(lg&1)
    const unsigned short* abase = A + (size_t)(rbase + lr) * 16 + (lg & 1) * 8;
#pragma unroll
    for (int ks = 0; ks < 4; ++ks) {
      short8v a = *reinterpret_cast<const short8v*>(abase + (size_t)(2 * ks + (lg >> 1)) * strideS);
#pragma unroll
      for (int jt = 0; jt < 8; ++jt) {
        short8v b = *reinterpret_cast<const short8v*>(&Wl[(jt * 16 + lr) * 136 + ks * 32 + lg * 8]);
        acc[jt] = __builtin_amdgcn_mfma_f32_16x16x32_bf16(a, b, acc[jt], 0, 0, 0);
      }
    }
    float vals[8][4];
    float ss[4] = {0.f, 0.f, 0.f, 0.f};
#pragma unroll
    for (int jt = 0; jt < 8; ++jt) {
      float bj = bias[jt * 16 + lr];
#pragma unroll
      for (int i = 0; i < 4; ++i) {
        float t = acc[jt][i] + bj;
        t = (t > 0.f) ? t : LEAKY * t;
        vals[jt][i] = t;
        ss[i] += t * t;
      }
    }
#pragma unroll
    for (int i = 0; i < 4; ++i) {
      float s = ss[i];
      s += __shfl_xor(s, 1); s += __shfl_xor(s, 2);
      s += __shfl_xor(s, 4); s += __shfl_xor(s, 8);
      ss[i] = 1.0f / fmaxf(sqrtf(s), 1e-12f);
    }
#pragma unroll
    for (int i = 0; i < 4; ++i) {
      int row = rbase + lg * 4 + i;
      if (row < n) {
#pragma unroll
        for (int jt = 0; jt < 8; ++jt)  // slice jt, offset lr
          enc[(size_t)jt * strideS + (size_t)row * 16 + lr] =
              (unsigned short)f2bf(vals[jt][i] * ss[i]);
      }
    }
  }
}

// ---------------- gather + attention ----------------

__global__ void gather_tar(const unsigned short* __restrict__ src,
                           const int* __restrict__ poi_idx, float* __restrict__ tar,
                           int B, size_t strideS) {
  int j = blockIdx.x;
  if (j < B) {
    int t = threadIdx.x;  // 64 threads; features 2t, 2t+1
    int f = t * 2;
    size_t idx = (size_t)poi_idx[j];
    unsigned u = *reinterpret_cast<const unsigned*>(
        src + (size_t)(f >> 4) * strideS + idx * 16 + (f & 15));
    reinterpret_cast<float2*>(tar + (size_t)j * D)[t] = make_float2(bflo2f(u), bfhi2f(u));
  }
}

// qkv via MFMA with fused x_idx row gather from slice-major enc.
__global__ __launch_bounds__(256) void qkv_mfma(
    const unsigned short* __restrict__ enc, const int* __restrict__ x_idx,
    const unsigned short* __restrict__ Wb, const float* __restrict__ bias,
    float* __restrict__ qkv, int M, size_t strideS) {
  __shared__ unsigned short Wl[128 * 136];
  int tid = threadIdx.x;
  const unsigned short* Wslab = Wb + (size_t)blockIdx.y * 128 * D;
  {
    int cg = (tid & 15) * 8;
    int r0 = tid >> 4;
#pragma unroll
    for (int i = 0; i < 8; ++i) {
      int row = r0 + i * 16;
      *reinterpret_cast<short8v*>(&Wl[row * 136 + cg]) =
          *reinterpret_cast<const short8v*>(Wslab + row * D + cg);
    }
  }
  __syncthreads();
  int w = tid >> 6, lane = tid & 63;
  int lr = lane & 15, lg = lane >> 4;
  int colbase = blockIdx.y * 128;
#pragma unroll
  for (int rt = 0; rt < 2; ++rt) {
    int rbase = blockIdx.x * 128 + rt * 64 + w * 16;
    f32x4 acc[8];
#pragma unroll
    for (int j = 0; j < 8; ++j) acc[j] = f32x4{0.f, 0.f, 0.f, 0.f};
    const unsigned short* abase =
        enc + (size_t)x_idx[rbase + lr] * 16 + (lg & 1) * 8;
#pragma unroll
    for (int ks = 0; ks < 4; ++ks) {
      short8v a = *reinterpret_cast<const short8v*>(abase + (size_t)(2 * ks + (lg >> 1)) * strideS);
#pragma unroll
      for (int jt = 0; jt < 8; ++jt) {
        short8v b = *reinterpret_cast<const short8v*>(&Wl[(jt * 16 + lr) * 136 + ks * 32 + lg * 8]);
        acc[jt] = __builtin_amdgcn_mfma_f32_16x16x32_bf16(a, b, acc[jt], 0, 0, 0);
      }
    }
#pragma unroll
    for (int jt = 0; jt < 8; ++jt) {
      int j = colbase + jt * 16 + lr;
      float bj = bias[j];
#pragma unroll
      for (int i = 0; i < 4; ++i) {
        int row = rbase + lg * 4 + i;
        if (row < M) qkv[(size_t)row * 384 + j] = acc[jt][i] + bj;
      }
    }
  }
}

__global__ __launch_bounds__(128) void attn_kernel(
    const float* __restrict__ qkv, float* __restrict__ o) {
  __shared__ float k_s[L_SEQ][HD];
  __shared__ float v_s[L_SEQ][HD];
  __shared__ float sc[L_SEQ][L_SEQ + 1];
  int b = blockIdx.x / HEADS;
  int h = blockIdx.x % HEADS;
  int tid = threadIdx.x;
  const size_t rowbase = (size_t)b * L_SEQ;
  for (int idx = tid; idx < L_SEQ * HD; idx += 128) {
    int l = idx >> 4, d2 = idx & 15;
    const float* base = qkv + (rowbase + l) * 384 + h * HD + d2;
    k_s[l][d2] = base[128];
    v_s[l][d2] = base[256];
  }
  __syncthreads();
  if (tid < L_SEQ) {
    float q[HD];
    const float* qp = qkv + (rowbase + tid) * 384 + h * HD;
#pragma unroll
    for (int d2 = 0; d2 < HD; ++d2) q[d2] = qp[d2];
    float m = -1e30f;
    for (int j = 0; j < L_SEQ; ++j) {
      float s = 0.f;
#pragma unroll
      for (int d2 = 0; d2 < HD; ++d2) s += q[d2] * k_s[j][d2];
      s *= 0.25f;
      sc[tid][j] = s;
      m = fmaxf(m, s);
    }
    float sum = 0.f;
    for (int j = 0; j < L_SEQ; ++j) {
      float e = expf(sc[tid][j] - m);
      sc[tid][j] = e;
      sum += e;
    }
    float inv = 1.f / sum;
    float oacc[HD];
#pragma unroll
    for (int d2 = 0; d2 < HD; ++d2) oacc[d2] = 0.f;
    for (int j = 0; j < L_SEQ; ++j) {
      float p = sc[tid][j];
#pragma unroll
      for (int d2 = 0; d2 < HD; ++d2) oacc[d2] += p * v_s[j][d2];
    }
    float* op = o + (rowbase + tid) * D + h * HD;
#pragma unroll
    for (int d2 = 0; d2 < HD; ++d2) op[d2] = oacc[d2] * inv;
  }
}

__global__ __launch_bounds__(128) void out_mean_kernel(
    const float* __restrict__ o, const float* __restrict__ Wo,
    const float* __restrict__ bo, float* __restrict__ out, int L) {
  __shared__ float m_s[D];
  int b = blockIdx.x, tid = threadIdx.x;
  float s = 0.f;
  for (int l = 0; l < L; ++l) s += o[((size_t)b * L + l) * D + tid];
  m_s[tid] = s / (float)L;
  __syncthreads();
  const float4* w4 = reinterpret_cast<const float4*>(Wo + (size_t)tid * D);
  float acc = 0.f;
  for (int k4 = 0; k4 < D / 4; ++k4) {
    float4 w = w4[k4];
    int k = k4 * 4;
    acc += m_s[k] * w.x + m_s[k + 1] * w.y + m_s[k + 2] * w.z + m_s[k + 3] * w.w;
  }
  out[(size_t)b * D + tid] = acc + bo[tid];
}

// ---------------- launch ----------------

extern "C" void kernel_launch(void* const* d_in, const int* in_sizes, int n_in,
                              void* d_out, int out_size, void* d_ws, size_t ws_size,
                              hipStream_t stream) {
  const float* embeds   = (const float*)d_in[0];
  const float* gcn_W    = (const float*)d_in[1];
  const float* gcn_b    = (const float*)d_in[2];
  const float* in_w     = (const float*)d_in[3];
  const float* in_b     = (const float*)d_in[4];
  const float* out_w    = (const float*)d_in[5];
  const float* out_b    = (const float*)d_in[6];
  const float* dist_vec = (const float*)d_in[7];
  const int*   edges    = (const int*)d_in[8];
  const int*   x_idx    = (const int*)d_in[9];
  const int*   poi_idx  = (const int*)d_in[10];
  float* out = (float*)d_out;

  int N  = in_sizes[0] / D;   // 50000
  int E  = in_sizes[7];       // 400000
  int BL = in_sizes[9];       // 6400
  int B  = in_sizes[10];      // 64
  int L  = BL / B;            // 100
  const int* e0 = edges;
  const int* e1 = edges + E;
  size_t total_edges = (size_t)2 * E + N;          // 850000
  int Npad = ((N + 127) / 128) * 128;              // 50048
  int NB   = (N + 1023) / 1024;                    // 49 (<= 64)
  size_t strideS = (size_t)Npad * 16;              // elements per feature-slice

  char* p = (char*)d_ws;
  auto alloc = [&](size_t bytes) { char* q = p; p += (bytes + 255) & ~(size_t)255; return q; };
  int*      deg      = (int*)alloc((size_t)N * 4);
  int*      row_ptr  = (int*)alloc((size_t)(N + 1) * 4);
  int*      cursor   = (int*)alloc((size_t)N * 4);
  int*      bsum     = (int*)alloc((size_t)NB * 4);
  int*      spmm_ctr = (int*)alloc((size_t)GCN_NUM * 8 * 4);
  unsigned* ecw      = (unsigned*)alloc(total_edges * 4);
  unsigned short* emb_bf = (unsigned short*)alloc((size_t)Npad * D * 2);  // slice-major
  unsigned short* W_bf   = (unsigned short*)alloc((size_t)GCN_NUM * D * D * 2);
  unsigned short* inw_bf = (unsigned short*)alloc((size_t)3 * D * D * 2);
  unsigned short* agg_bf = (unsigned short*)alloc((size_t)Npad * D * 2);  // slice-major
  unsigned short* enc_bf = (unsigned short*)alloc((size_t)Npad * D * 2);  // slice-major
  float* qkv  = (float*)alloc((size_t)BL * 384 * 4);
  float* obuf = (float*)alloc((size_t)BL * D * 4);

  // fused converts + deg init + spmm queue zero
  int n4e = N * D / 4, n4w = GCN_NUM * D * D / 4, n4i = 3 * D * D / 4;
  int prep_tot = n4e + n4w + n4i + N;
  prep<<<(prep_tot + 255) / 256, 256, 0, stream>>>(
      embeds, emb_bf, n4e, gcn_W, W_bf, n4w, in_w, inw_bf, n4i, deg, N, spmm_ctr, strideS);

  // graph build
  count_deg<<<1024, 256, 0, stream>>>(e0, e1, deg, E);
  block_sum<<<NB, 1024, 0, stream>>>(deg, bsum, N);
  scan_final<<<NB, 1024, 0, stream>>>(deg, bsum, row_ptr, cursor, N, NB);
  int span = (N + SC_BUCKETS - 1) / SC_BUCKETS;
  int bpb = 512;
  scatter_edges_p<<<SC_BUCKETS * bpb, 256, 0, stream>>>(
      e0, e1, dist_vec, deg, cursor, ecw, E, N, span, bpb);

  // GCN layers (bf16 slice-major storage, XCD-local SpMM, MFMA dense)
  const unsigned short* cur_in = emb_bf;
  for (int i = 0; i < GCN_NUM; ++i) {
    spmm_slice<<<2048, 256, 0, stream>>>(row_ptr, ecw, cur_in, agg_bf,
                                         spmm_ctr + i * 8, N, strideS);
    dense_mfma<<<Npad / 128, 256, 0, stream>>>(
        agg_bf, W_bf + (size_t)i * D * D, gcn_b + (size_t)i * D, enc_bf, N, strideS);
    cur_in = enc_bf;
  }

  // gathers + attention
  gather_tar<<<B, 64, 0, stream>>>(enc_bf, poi_idx, out + (size_t)B * D, B, strideS);
  dim3 qgrid(BL / 128, 3);
  qkv_mfma<<<qgrid, 256, 0, stream>>>(enc_bf, x_idx, inw_bf, in_b, qkv, BL, strideS);
  attn_kernel<<<B * HEADS, 128, 0, stream>>>(qkv, obuf);
  out_mean_kernel<<<B, 128, 0, stream>>>(obuf, out_w, out_b, out, L);
}

// Round 11
// 477.360 us; speedup vs baseline: 1.2843x; 1.2843x over previous
//
#include <hip/hip_runtime.h>
#include <math.h>

#define D 128
#define GCN_NUM 3
#define HEADS 8
#define HD 16
#define L_SEQ 100
#define LEAKY 0.01f
#define SC_BUCKETS 8
#define NSLICE 4                 // 4 slices x 32 features

typedef __attribute__((ext_vector_type(8))) short short8v;
typedef __attribute__((ext_vector_type(4))) float f32x4;

__device__ __forceinline__ unsigned f2bf(float x) {
  unsigned u = __float_as_uint(x);
  return (u + 0x7FFFu + ((u >> 16) & 1u)) >> 16;
}
__device__ __forceinline__ float bflo2f(unsigned u) { return __uint_as_float(u << 16); }
__device__ __forceinline__ float bfhi2f(unsigned u) { return __uint_as_float(u & 0xFFFF0000u); }

// ---------------- prep: converts (embeds -> slice-major bf16; weights linear) + deg init ----------------

__global__ void prep(const float* __restrict__ s0, unsigned short* __restrict__ d0, int n0,
                     const float* __restrict__ s1, unsigned short* __restrict__ d1, int n1,
                     const float* __restrict__ s2, unsigned short* __restrict__ d2, int n2,
                     int* __restrict__ deg, int N, size_t strideS) {
  int i = blockIdx.x * blockDim.x + threadIdx.x;
  int n4tot = n0 + n1 + n2;
  if (i < n0) {
    // embeds -> slice-major [4][Npad][32]
    float4 v = reinterpret_cast<const float4*>(s0)[i];
    int row = i >> 5;          // 32 float4 per row
    int k = (i & 31) * 4;      // feature index of v.x
    uint2 o;
    o.x = f2bf(v.x) | (f2bf(v.y) << 16);
    o.y = f2bf(v.z) | (f2bf(v.w) << 16);
    unsigned short* dst = d0 + (size_t)(k >> 5) * strideS + (size_t)row * 32 + (k & 31);
    *reinterpret_cast<uint2*>(dst) = o;
  } else if (i < n4tot) {
    const float* s; unsigned short* d; int j;
    if (i < n0 + n1) { s = s1; d = d1; j = i - n0; }
    else             { s = s2; d = d2; j = i - n0 - n1; }
    float4 v = reinterpret_cast<const float4*>(s)[j];
    uint2 o;
    o.x = f2bf(v.x) | (f2bf(v.y) << 16);
    o.y = f2bf(v.z) | (f2bf(v.w) << 16);
    reinterpret_cast<uint2*>(d)[j] = o;
  } else if (i - n4tot < N) {
    deg[i - n4tot] = 1;  // self-loop
  }
}

// ---------------- graph build ----------------

__global__ void count_deg(const int* __restrict__ e0, const int* __restrict__ e1,
                          int* __restrict__ deg, int E) {
  int stride = gridDim.x * blockDim.x;
  for (int i = blockIdx.x * blockDim.x + threadIdx.x; i < E; i += stride) {
    atomicAdd(&deg[e0[i]], 1);
    atomicAdd(&deg[e1[i]], 1);
  }
}

__global__ __launch_bounds__(1024) void block_sum(const int* __restrict__ deg,
                                                  int* __restrict__ bsum, int n) {
  __shared__ int ws[16];
  int tid = threadIdx.x, lane = tid & 63, wid = tid >> 6;
  int i = blockIdx.x * 1024 + tid;
  int v = (i < n) ? deg[i] : 0;
#pragma unroll
  for (int off = 32; off; off >>= 1) v += __shfl_xor(v, off);
  if (lane == 0) ws[wid] = v;
  __syncthreads();
  if (tid == 0) {
    int s = 0;
#pragma unroll
    for (int k = 0; k < 16; ++k) s += ws[k];
    bsum[blockIdx.x] = s;
  }
}

__global__ __launch_bounds__(1024) void scan_final(
    const int* __restrict__ deg, const int* __restrict__ bsum,
    int* __restrict__ row_ptr, int* __restrict__ cursor, int n, int nb) {
  __shared__ int ws[16];
  __shared__ int prefix_s;
  int tid = threadIdx.x, lane = tid & 63, wid = tid >> 6;
  int i = blockIdx.x * 1024 + tid;
  int v = (i < n) ? deg[i] : 0;
  int x = v;
#pragma unroll
  for (int off = 1; off < 64; off <<= 1) {
    int y = __shfl_up(x, off);
    if (lane >= off) x += y;
  }
  if (lane == 63) ws[wid] = x;
  __syncthreads();
  if (wid == 0) {
    int pv = (lane < blockIdx.x) ? bsum[lane] : 0;
#pragma unroll
    for (int off = 32; off; off >>= 1) pv += __shfl_xor(pv, off);
    if (lane == 0) prefix_s = pv;
    int s = (lane < 16) ? ws[lane] : 0;
#pragma unroll
    for (int off = 1; off < 16; off <<= 1) {
      int y = __shfl_up(s, off);
      if (lane >= off) s += y;
    }
    if (lane < 16) ws[lane] = s;
  }
  __syncthreads();
  int woff = wid ? ws[wid - 1] : 0;
  int prefix = prefix_s;
  if (i < n) {
    int pval = prefix + woff + (x - v);
    row_ptr[i] = pval;
    cursor[i] = pval;
  }
  if (blockIdx.x == nb - 1 && tid == 0) row_ptr[n] = prefix + ws[15];
}

// bucketed scatter, 4-byte packed descriptor (col u16 | bf16 w << 16)
__global__ __launch_bounds__(256) void scatter_edges_p(
    const int* __restrict__ e0, const int* __restrict__ e1,
    const float* __restrict__ dv, const int* __restrict__ deg,
    int* __restrict__ cursor, unsigned* __restrict__ ecw,
    int E, int N, int span, int bpb) {
  int bucket = blockIdx.x & (SC_BUCKETS - 1);
  int bx = blockIdx.x >> 3;
  int rlo = bucket * span;
  int rhi = min(rlo + span, N);
  int total = 2 * E + N;
  int stride = bpb * 256;
  for (int i = bx * 256 + threadIdx.x; i < total; i += stride) {
    int r, c; bool self = false;
    if (i < E)          { r = e0[i];     c = e1[i]; }
    else if (i < 2 * E) { r = e1[i - E]; c = e0[i - E]; }
    else                { r = i - 2 * E; c = r; self = true; }
    if (r < rlo || r >= rhi) continue;
    float d = self ? 0.f : dv[(i < E) ? i : i - E];
    float w = expf(-d * d) * (1.0f / sqrtf((float)deg[r])) * (1.0f / sqrtf((float)deg[c]));
    int pos = atomicAdd(&cursor[r], 1);
    ecw[pos] = (unsigned)c | (f2bf(w) << 16);
  }
}

// ---------------- GCN ----------------

// Sliced SpMM, round-9 load shape: wave per (row, slice); slice = bid&3 -> one
// 3.2MB slice per XCD (round-robin bid->XCD). 64 lanes = 16 edge-groups x 4 lanes;
// each lane loads uint4 (16B) -> full 64B line per edge, 16 edges in flight.
__global__ __launch_bounds__(256) void spmm_s4(
    const int* __restrict__ row_ptr, const unsigned* __restrict__ ecw,
    const unsigned short* __restrict__ in_s, unsigned short* __restrict__ out_s,
    int n, size_t strideS) {
  int slice = blockIdx.x & (NSLICE - 1);
  int r = ((blockIdx.x >> 2) << 2) + (threadIdx.x >> 6);
  if (r >= n) return;
  int lane = threadIdx.x & 63;
  int eg = lane >> 2, fl = lane & 3;   // edge group, feature quad (8 features)
  const unsigned short* in = in_s + (size_t)slice * strideS;
  unsigned short* out = out_s + (size_t)slice * strideS;
  int s = row_ptr[r], e = row_ptr[r + 1];
  float a0 = 0.f, a1 = 0.f, a2 = 0.f, a3 = 0.f, a4 = 0.f, a5 = 0.f, a6 = 0.f, a7 = 0.f;
  int i = s + eg;
  unsigned d = (i < e) ? ecw[i] : 0u;   // sentinel: w=0, gathers row 0 (cached)
  int nit = (e - s + 15) >> 4;
  for (int it = 0; it < nit; ++it) {
    int inx = i + 16;
    unsigned dn = (inx < e) ? ecw[inx] : 0u;  // prefetch next descriptor
    float w = bfhi2f(d);
    uint4 u = *reinterpret_cast<const uint4*>(in + (size_t)(d & 0xFFFFu) * 32 + fl * 8);
    a0 = fmaf(w, bflo2f(u.x), a0); a1 = fmaf(w, bfhi2f(u.x), a1);
    a2 = fmaf(w, bflo2f(u.y), a2); a3 = fmaf(w, bfhi2f(u.y), a3);
    a4 = fmaf(w, bflo2f(u.z), a4); a5 = fmaf(w, bfhi2f(u.z), a5);
    a6 = fmaf(w, bflo2f(u.w), a6); a7 = fmaf(w, bfhi2f(u.w), a7);
    d = dn; i = inx;
  }
  // reduce across the 16 edge groups (lane bits 2..5)
#pragma unroll
  for (int off = 4; off < 64; off <<= 1) {
    a0 += __shfl_xor(a0, off); a1 += __shfl_xor(a1, off);
    a2 += __shfl_xor(a2, off); a3 += __shfl_xor(a3, off);
    a4 += __shfl_xor(a4, off); a5 += __shfl_xor(a5, off);
    a6 += __shfl_xor(a6, off); a7 += __shfl_xor(a7, off);
  }
  if (eg == 0) {
    uint4 o;
    o.x = f2bf(a0) | (f2bf(a1) << 16);
    o.y = f2bf(a2) | (f2bf(a3) << 16);
    o.z = f2bf(a4) | (f2bf(a5) << 16);
    o.w = f2bf(a6) | (f2bf(a7) << 16);
    *reinterpret_cast<uint4*>(out + (size_t)r * 32 + fl * 8) = o;
  }
}

// enc = normalize(leaky_relu(A @ W^T + b)) via MFMA bf16; A and enc slice-major [4][Npad][32].
__global__ __launch_bounds__(256) void dense_mfma(
    const unsigned short* __restrict__ A, const unsigned short* __restrict__ Wb,
    const float* __restrict__ bias, unsigned short* __restrict__ enc,
    int n, size_t strideS) {
  __shared__ unsigned short Wl[128 * 136];
  int tid = threadIdx.x;
  {
    int cg = (tid & 15) * 8;
    int r0 = tid >> 4;
#pragma unroll
    for (int i = 0; i < 8; ++i) {
      int row = r0 + i * 16;
      *reinterpret_cast<short8v*>(&Wl[row * 136 + cg]) =
          *reinterpret_cast<const short8v*>(Wb + row * D + cg);
    }
  }
  __syncthreads();
  int w = tid >> 6, lane = tid & 63;
  int lr = lane & 15, lg = lane >> 4;
#pragma unroll
  for (int rt = 0; rt < 2; ++rt) {
    int rbase = blockIdx.x * 128 + rt * 64 + w * 16;
    f32x4 acc[8];
#pragma unroll
    for (int j = 0; j < 8; ++j) acc[j] = f32x4{0.f, 0.f, 0.f, 0.f};
    // A fragment k = ks*32 + lg*8 -> slice ks, offset lg*8
    const unsigned short* abase = A + (size_t)(rbase + lr) * 32 + lg * 8;
#pragma unroll
    for (int ks = 0; ks < 4; ++ks) {
      short8v a = *reinterpret_cast<const short8v*>(abase + (size_t)ks * strideS);
#pragma unroll
      for (int jt = 0; jt < 8; ++jt) {
        short8v b = *reinterpret_cast<const short8v*>(&Wl[(jt * 16 + lr) * 136 + ks * 32 + lg * 8]);
        acc[jt] = __builtin_amdgcn_mfma_f32_16x16x32_bf16(a, b, acc[jt], 0, 0, 0);
      }
    }
    float vals[8][4];
    float ss[4] = {0.f, 0.f, 0.f, 0.f};
#pragma unroll
    for (int jt = 0; jt < 8; ++jt) {
      float bj = bias[jt * 16 + lr];
#pragma unroll
      for (int i = 0; i < 4; ++i) {
        float t = acc[jt][i] + bj;
        t = (t > 0.f) ? t : LEAKY * t;
        vals[jt][i] = t;
        ss[i] += t * t;
      }
    }
#pragma unroll
    for (int i = 0; i < 4; ++i) {
      float s = ss[i];
      s += __shfl_xor(s, 1); s += __shfl_xor(s, 2);
      s += __shfl_xor(s, 4); s += __shfl_xor(s, 8);
      ss[i] = 1.0f / fmaxf(sqrtf(s), 1e-12f);
    }
#pragma unroll
    for (int i = 0; i < 4; ++i) {
      int row = rbase + lg * 4 + i;
      if (row < n) {
#pragma unroll
        for (int jt = 0; jt < 8; ++jt) {  // out col j = jt*16+lr -> slice jt>>1, offset (jt&1)*16+lr
          enc[(size_t)(jt >> 1) * strideS + (size_t)row * 32 + (jt & 1) * 16 + lr] =
              (unsigned short)f2bf(vals[jt][i] * ss[i]);
        }
      }
    }
  }
}

// ---------------- gather + attention ----------------

__global__ void gather_tar(const unsigned short* __restrict__ src,
                           const int* __restrict__ poi_idx, float* __restrict__ tar,
                           int B, size_t strideS) {
  int j = blockIdx.x;
  if (j < B) {
    int t = threadIdx.x;  // 64 threads; features 2t, 2t+1
    int f = t * 2;
    size_t idx = (size_t)poi_idx[j];
    unsigned u = *reinterpret_cast<const unsigned*>(
        src + (size_t)(f >> 5) * strideS + idx * 32 + (f & 31));
    reinterpret_cast<float2*>(tar + (size_t)j * D)[t] = make_float2(bflo2f(u), bfhi2f(u));
  }
}

// qkv via MFMA with fused x_idx row gather from slice-major enc.
__global__ __launch_bounds__(256) void qkv_mfma(
    const unsigned short* __restrict__ enc, const int* __restrict__ x_idx,
    const unsigned short* __restrict__ Wb, const float* __restrict__ bias,
    float* __restrict__ qkv, int M, size_t strideS) {
  __shared__ unsigned short Wl[128 * 136];
  int tid = threadIdx.x;
  const unsigned short* Wslab = Wb + (size_t)blockIdx.y * 128 * D;
  {
    int cg = (tid & 15) * 8;
    int r0 = tid >> 4;
#pragma unroll
    for (int i = 0; i < 8; ++i) {
      int row = r0 + i * 16;
      *reinterpret_cast<short8v*>(&Wl[row * 136 + cg]) =
          *reinterpret_cast<const short8v*>(Wslab + row * D + cg);
    }
  }
  __syncthreads();
  int w = tid >> 6, lane = tid & 63;
  int lr = lane & 15, lg = lane >> 4;
  int colbase = blockIdx.y * 128;
#pragma unroll
  for (int rt = 0; rt < 2; ++rt) {
    int rbase = blockIdx.x * 128 + rt * 64 + w * 16;
    f32x4 acc[8];
#pragma unroll
    for (int j = 0; j < 8; ++j) acc[j] = f32x4{0.f, 0.f, 0.f, 0.f};
    const unsigned short* abase = enc + (size_t)x_idx[rbase + lr] * 32 + lg * 8;
#pragma unroll
    for (int ks = 0; ks < 4; ++ks) {
      short8v a = *reinterpret_cast<const short8v*>(abase + (size_t)ks * strideS);
#pragma unroll
      for (int jt = 0; jt < 8; ++jt) {
        short8v b = *reinterpret_cast<const short8v*>(&Wl[(jt * 16 + lr) * 136 + ks * 32 + lg * 8]);
        acc[jt] = __builtin_amdgcn_mfma_f32_16x16x32_bf16(a, b, acc[jt], 0, 0, 0);
      }
    }
#pragma unroll
    for (int jt = 0; jt < 8; ++jt) {
      int j = colbase + jt * 16 + lr;
      float bj = bias[j];
#pragma unroll
      for (int i = 0; i < 4; ++i) {
        int row = rbase + lg * 4 + i;
        if (row < M) qkv[(size_t)row * 384 + j] = acc[jt][i] + bj;
      }
    }
  }
}

__global__ __launch_bounds__(128) void attn_kernel(
    const float* __restrict__ qkv, float* __restrict__ o) {
  __shared__ float k_s[L_SEQ][HD];
  __shared__ float v_s[L_SEQ][HD];
  __shared__ float sc[L_SEQ][L_SEQ + 1];
  int b = blockIdx.x / HEADS;
  int h = blockIdx.x % HEADS;
  int tid = threadIdx.x;
  const size_t rowbase = (size_t)b * L_SEQ;
  for (int idx = tid; idx < L_SEQ * HD; idx += 128) {
    int l = idx >> 4, d2 = idx & 15;
    const float* base = qkv + (rowbase + l) * 384 + h * HD + d2;
    k_s[l][d2] = base[128];
    v_s[l][d2] = base[256];
  }
  __syncthreads();
  if (tid < L_SEQ) {
    float q[HD];
    const float* qp = qkv + (rowbase + tid) * 384 + h * HD;
#pragma unroll
    for (int d2 = 0; d2 < HD; ++d2) q[d2] = qp[d2];
    float m = -1e30f;
    for (int j = 0; j < L_SEQ; ++j) {
      float s = 0.f;
#pragma unroll
      for (int d2 = 0; d2 < HD; ++d2) s += q[d2] * k_s[j][d2];
      s *= 0.25f;
      sc[tid][j] = s;
      m = fmaxf(m, s);
    }
    float sum = 0.f;
    for (int j = 0; j < L_SEQ; ++j) {
      float e = expf(sc[tid][j] - m);
      sc[tid][j] = e;
      sum += e;
    }
    float inv = 1.f / sum;
    float oacc[HD];
#pragma unroll
    for (int d2 = 0; d2 < HD; ++d2) oacc[d2] = 0.f;
    for (int j = 0; j < L_SEQ; ++j) {
      float p = sc[tid][j];
#pragma unroll
      for (int d2 = 0; d2 < HD; ++d2) oacc[d2] += p * v_s[j][d2];
    }
    float* op = o + (rowbase + tid) * D + h * HD;
#pragma unroll
    for (int d2 = 0; d2 < HD; ++d2) op[d2] = oacc[d2] * inv;
  }
}

__global__ __launch_bounds__(128) void out_mean_kernel(
    const float* __restrict__ o, const float* __restrict__ Wo,
    const float* __restrict__ bo, float* __restrict__ out, int L) {
  __shared__ float m_s[D];
  int b = blockIdx.x, tid = threadIdx.x;
  float s = 0.f;
  for (int l = 0; l < L; ++l) s += o[((size_t)b * L + l) * D + tid];
  m_s[tid] = s / (float)L;
  __syncthreads();
  const float4* w4 = reinterpret_cast<const float4*>(Wo + (size_t)tid * D);
  float acc = 0.f;
  for (int k4 = 0; k4 < D / 4; ++k4) {
    float4 w = w4[k4];
    int k = k4 * 4;
    acc += m_s[k] * w.x + m_s[k + 1] * w.y + m_s[k + 2] * w.z + m_s[k + 3] * w.w;
  }
  out[(size_t)b * D + tid] = acc + bo[tid];
}

// ---------------- launch ----------------

extern "C" void kernel_launch(void* const* d_in, const int* in_sizes, int n_in,
                              void* d_out, int out_size, void* d_ws, size_t ws_size,
                              hipStream_t stream) {
  const float* embeds   = (const float*)d_in[0];
  const float* gcn_W    = (const float*)d_in[1];
  const float* gcn_b    = (const float*)d_in[2];
  const float* in_w     = (const float*)d_in[3];
  const float* in_b     = (const float*)d_in[4];
  const float* out_w    = (const float*)d_in[5];
  const float* out_b    = (const float*)d_in[6];
  const float* dist_vec = (const float*)d_in[7];
  const int*   edges    = (const int*)d_in[8];
  const int*   x_idx    = (const int*)d_in[9];
  const int*   poi_idx  = (const int*)d_in[10];
  float* out = (float*)d_out;

  int N  = in_sizes[0] / D;   // 50000
  int E  = in_sizes[7];       // 400000
  int BL = in_sizes[9];       // 6400
  int B  = in_sizes[10];      // 64
  int L  = BL / B;            // 100
  const int* e0 = edges;
  const int* e1 = edges + E;
  size_t total_edges = (size_t)2 * E + N;          // 850000
  int Npad = ((N + 127) / 128) * 128;              // 50048
  int NB   = (N + 1023) / 1024;                    // 49 (<= 64)
  size_t strideS = (size_t)Npad * 32;              // elements per 32-feature slice

  char* p = (char*)d_ws;
  auto alloc = [&](size_t bytes) { char* q = p; p += (bytes + 255) & ~(size_t)255; return q; };
  int*      deg     = (int*)alloc((size_t)N * 4);
  int*      row_ptr = (int*)alloc((size_t)(N + 1) * 4);
  int*      cursor  = (int*)alloc((size_t)N * 4);
  int*      bsum    = (int*)alloc((size_t)NB * 4);
  unsigned* ecw     = (unsigned*)alloc(total_edges * 4);
  unsigned short* emb_bf = (unsigned short*)alloc((size_t)Npad * D * 2);  // slice-major
  unsigned short* W_bf   = (unsigned short*)alloc((size_t)GCN_NUM * D * D * 2);
  unsigned short* inw_bf = (unsigned short*)alloc((size_t)3 * D * D * 2);
  unsigned short* agg_bf = (unsigned short*)alloc((size_t)Npad * D * 2);  // slice-major
  unsigned short* enc_bf = (unsigned short*)alloc((size_t)Npad * D * 2);  // slice-major
  float* qkv  = (float*)alloc((size_t)BL * 384 * 4);
  float* obuf = (float*)alloc((size_t)BL * D * 4);

  // fused converts + deg init
  int n4e = N * D / 4, n4w = GCN_NUM * D * D / 4, n4i = 3 * D * D / 4;
  int prep_tot = n4e + n4w + n4i + N;
  prep<<<(prep_tot + 255) / 256, 256, 0, stream>>>(
      embeds, emb_bf, n4e, gcn_W, W_bf, n4w, in_w, inw_bf, n4i, deg, N, strideS);

  // graph build
  count_deg<<<1024, 256, 0, stream>>>(e0, e1, deg, E);
  block_sum<<<NB, 1024, 0, stream>>>(deg, bsum, N);
  scan_final<<<NB, 1024, 0, stream>>>(deg, bsum, row_ptr, cursor, N, NB);
  int span = (N + SC_BUCKETS - 1) / SC_BUCKETS;
  int bpb = 512;
  scatter_edges_p<<<SC_BUCKETS * bpb, 256, 0, stream>>>(
      e0, e1, dist_vec, deg, cursor, ecw, E, N, span, bpb);

  // GCN layers (bf16 slice-major storage, sliced SpMM, MFMA dense)
  int spmm_grid = ((N + 3) / 4) * NSLICE;
  const unsigned short* cur_in = emb_bf;
  for (int i = 0; i < GCN_NUM; ++i) {
    spmm_s4<<<spmm_grid, 256, 0, stream>>>(row_ptr, ecw, cur_in, agg_bf, N, strideS);
    dense_mfma<<<Npad / 128, 256, 0, stream>>>(
        agg_bf, W_bf + (size_t)i * D * D, gcn_b + (size_t)i * D, enc_bf, N, strideS);
    cur_in = enc_bf;
  }

  // gathers + attention
  gather_tar<<<B, 64, 0, stream>>>(enc_bf, poi_idx, out + (size_t)B * D, B, strideS);
  dim3 qgrid(BL / 128, 3);
  qkv_mfma<<<qgrid, 256, 0, stream>>>(enc_bf, x_idx, inw_bf, in_b, qkv, BL, strideS);
  attn_kernel<<<B * HEADS, 128, 0, stream>>>(qkv, obuf);
  out_mean_kernel<<<B, 128, 0, stream>>>(obuf, out_w, out_b, out, L);
}

// Round 12
// 371.746 us; speedup vs baseline: 1.6492x; 1.2841x over previous
//
#include <hip/hip_runtime.h>
#include <math.h>

#define D 128
#define GCN_NUM 3
#define HEADS 8
#define HD 16
#define L_SEQ 100
#define LEAKY 0.01f
#define SC_BUCKETS 8
#define NSLICE 4                 // 4 slices x 32 features

typedef __attribute__((ext_vector_type(8))) short short8v;
typedef __attribute__((ext_vector_type(4))) float f32x4;

__device__ __forceinline__ unsigned f2bf(float x) {
  unsigned u = __float_as_uint(x);
  return (u + 0x7FFFu + ((u >> 16) & 1u)) >> 16;
}
__device__ __forceinline__ float bflo2f(unsigned u) { return __uint_as_float(u << 16); }
__device__ __forceinline__ float bfhi2f(unsigned u) { return __uint_as_float(u & 0xFFFF0000u); }

// ---------------- prep: converts (embeds -> slice-major bf16; weights linear) + deg init ----------------

__global__ void prep(const float* __restrict__ s0, unsigned short* __restrict__ d0, int n0,
                     const float* __restrict__ s1, unsigned short* __restrict__ d1, int n1,
                     const float* __restrict__ s2, unsigned short* __restrict__ d2, int n2,
                     int* __restrict__ deg, int N, size_t strideS) {
  int i = blockIdx.x * blockDim.x + threadIdx.x;
  int n4tot = n0 + n1 + n2;
  if (i < n0) {
    // embeds -> slice-major [4][Npad][32]
    float4 v = reinterpret_cast<const float4*>(s0)[i];
    int row = i >> 5;          // 32 float4 per row
    int k = (i & 31) * 4;      // feature index of v.x
    uint2 o;
    o.x = f2bf(v.x) | (f2bf(v.y) << 16);
    o.y = f2bf(v.z) | (f2bf(v.w) << 16);
    unsigned short* dst = d0 + (size_t)(k >> 5) * strideS + (size_t)row * 32 + (k & 31);
    *reinterpret_cast<uint2*>(dst) = o;
  } else if (i < n4tot) {
    const float* s; unsigned short* d; int j;
    if (i < n0 + n1) { s = s1; d = d1; j = i - n0; }
    else             { s = s2; d = d2; j = i - n0 - n1; }
    float4 v = reinterpret_cast<const float4*>(s)[j];
    uint2 o;
    o.x = f2bf(v.x) | (f2bf(v.y) << 16);
    o.y = f2bf(v.z) | (f2bf(v.w) << 16);
    reinterpret_cast<uint2*>(d)[j] = o;
  } else if (i - n4tot < N) {
    deg[i - n4tot] = 1;  // self-loop
  }
}

// ---------------- graph build ----------------

__global__ void count_deg(const int* __restrict__ e0, const int* __restrict__ e1,
                          int* __restrict__ deg, int E) {
  int stride = gridDim.x * blockDim.x;
  for (int i = blockIdx.x * blockDim.x + threadIdx.x; i < E; i += stride) {
    atomicAdd(&deg[e0[i]], 1);
    atomicAdd(&deg[e1[i]], 1);
  }
}

__global__ __launch_bounds__(1024) void block_sum(const int* __restrict__ deg,
                                                  int* __restrict__ bsum, int n) {
  __shared__ int ws[16];
  int tid = threadIdx.x, lane = tid & 63, wid = tid >> 6;
  int i = blockIdx.x * 1024 + tid;
  int v = (i < n) ? deg[i] : 0;
#pragma unroll
  for (int off = 32; off; off >>= 1) v += __shfl_xor(v, off);
  if (lane == 0) ws[wid] = v;
  __syncthreads();
  if (tid == 0) {
    int s = 0;
#pragma unroll
    for (int k = 0; k < 16; ++k) s += ws[k];
    bsum[blockIdx.x] = s;
  }
}

__global__ __launch_bounds__(1024) void scan_final(
    const int* __restrict__ deg, const int* __restrict__ bsum,
    int* __restrict__ row_ptr, int* __restrict__ cursor, int n, int nb) {
  __shared__ int ws[16];
  __shared__ int prefix_s;
  int tid = threadIdx.x, lane = tid & 63, wid = tid >> 6;
  int i = blockIdx.x * 1024 + tid;
  int v = (i < n) ? deg[i] : 0;
  int x = v;
#pragma unroll
  for (int off = 1; off < 64; off <<= 1) {
    int y = __shfl_up(x, off);
    if (lane >= off) x += y;
  }
  if (lane == 63) ws[wid] = x;
  __syncthreads();
  if (wid == 0) {
    int pv = (lane < blockIdx.x) ? bsum[lane] : 0;
#pragma unroll
    for (int off = 32; off; off >>= 1) pv += __shfl_xor(pv, off);
    if (lane == 0) prefix_s = pv;
    int s = (lane < 16) ? ws[lane] : 0;
#pragma unroll
    for (int off = 1; off < 16; off <<= 1) {
      int y = __shfl_up(s, off);
      if (lane >= off) s += y;
    }
    if (lane < 16) ws[lane] = s;
  }
  __syncthreads();
  int woff = wid ? ws[wid - 1] : 0;
  int prefix = prefix_s;
  if (i < n) {
    int pval = prefix + woff + (x - v);
    row_ptr[i] = pval;
    cursor[i] = pval;
  }
  if (blockIdx.x == nb - 1 && tid == 0) row_ptr[n] = prefix + ws[15];
}

// bucketed scatter, 4-byte packed descriptor (col u16 | bf16 w << 16)
__global__ __launch_bounds__(256) void scatter_edges_p(
    const int* __restrict__ e0, const int* __restrict__ e1,
    const float* __restrict__ dv, const int* __restrict__ deg,
    int* __restrict__ cursor, unsigned* __restrict__ ecw,
    int E, int N, int span, int bpb) {
  int bucket = blockIdx.x & (SC_BUCKETS - 1);
  int bx = blockIdx.x >> 3;
  int rlo = bucket * span;
  int rhi = min(rlo + span, N);
  int total = 2 * E + N;
  int stride = bpb * 256;
  for (int i = bx * 256 + threadIdx.x; i < total; i += stride) {
    int r, c; bool self = false;
    if (i < E)          { r = e0[i];     c = e1[i]; }
    else if (i < 2 * E) { r = e1[i - E]; c = e0[i - E]; }
    else                { r = i - 2 * E; c = r; self = true; }
    if (r < rlo || r >= rhi) continue;
    float d = self ? 0.f : dv[(i < E) ? i : i - E];
    float w = expf(-d * d) * (1.0f / sqrtf((float)deg[r])) * (1.0f / sqrtf((float)deg[c]));
    int pos = atomicAdd(&cursor[r], 1);
    ecw[pos] = (unsigned)c | (f2bf(w) << 16);
  }
}

// ---------------- GCN ----------------

// Sliced SpMM v2: wave = 4 rows x 1 slice. lane = r4*16 + eg*4 + fl.
// 4 edge-groups/row (24 slots vs deg~17), 2-level reduce, 16 gathers in flight,
// slice = bid&3 -> one 3.2MB slice per XCD (bid->XCD round-robin mod 8).
__global__ __launch_bounds__(256) void spmm_s44(
    const int* __restrict__ row_ptr, const unsigned* __restrict__ ecw,
    const unsigned short* __restrict__ in_s, unsigned short* __restrict__ out_s,
    int n, size_t strideS) {
  int slice = blockIdx.x & (NSLICE - 1);
  int lane = threadIdx.x & 63;
  int r4 = lane >> 4;          // row within wave
  int eg = (lane >> 2) & 3;    // edge group
  int fl = lane & 3;           // feature quad (8 features, 16B)
  int r = (blockIdx.x >> 2) * 16 + (threadIdx.x >> 6) * 4 + r4;
  bool rowok = r < n;
  int s = rowok ? row_ptr[r] : 0;
  int e = rowok ? row_ptr[r + 1] : 0;
  const unsigned short* in = in_s + (size_t)slice * strideS;
  unsigned short* out = out_s + (size_t)slice * strideS;
  float a0 = 0.f, a1 = 0.f, a2 = 0.f, a3 = 0.f, a4 = 0.f, a5 = 0.f, a6 = 0.f, a7 = 0.f;
  int i = s + eg;
  unsigned d = (i < e) ? ecw[i] : 0u;   // sentinel 0: w=0, gathers row 0 (cached)
  while (__any(i < e)) {
    int inx = i + 4;
    unsigned dn = (inx < e) ? ecw[inx] : 0u;  // prefetch next descriptor
    float w = bfhi2f(d);
    uint4 u = *reinterpret_cast<const uint4*>(in + (size_t)(d & 0xFFFFu) * 32 + fl * 8);
    a0 = fmaf(w, bflo2f(u.x), a0); a1 = fmaf(w, bfhi2f(u.x), a1);
    a2 = fmaf(w, bflo2f(u.y), a2); a3 = fmaf(w, bfhi2f(u.y), a3);
    a4 = fmaf(w, bflo2f(u.z), a4); a5 = fmaf(w, bfhi2f(u.z), a5);
    a6 = fmaf(w, bflo2f(u.w), a6); a7 = fmaf(w, bfhi2f(u.w), a7);
    d = dn; i = inx;
  }
  // reduce across the 4 edge groups (lane bits 2..3)
#pragma unroll
  for (int off = 4; off < 16; off <<= 1) {
    a0 += __shfl_xor(a0, off); a1 += __shfl_xor(a1, off);
    a2 += __shfl_xor(a2, off); a3 += __shfl_xor(a3, off);
    a4 += __shfl_xor(a4, off); a5 += __shfl_xor(a5, off);
    a6 += __shfl_xor(a6, off); a7 += __shfl_xor(a7, off);
  }
  if (eg == 0 && rowok) {
    uint4 o;
    o.x = f2bf(a0) | (f2bf(a1) << 16);
    o.y = f2bf(a2) | (f2bf(a3) << 16);
    o.z = f2bf(a4) | (f2bf(a5) << 16);
    o.w = f2bf(a6) | (f2bf(a7) << 16);
    *reinterpret_cast<uint4*>(out + (size_t)r * 32 + fl * 8) = o;
  }
}

// enc = normalize(leaky_relu(A @ W^T + b)) via MFMA bf16; A and enc slice-major [4][Npad][32].
__global__ __launch_bounds__(256) void dense_mfma(
    const unsigned short* __restrict__ A, const unsigned short* __restrict__ Wb,
    const float* __restrict__ bias, unsigned short* __restrict__ enc,
    int n, size_t strideS) {
  __shared__ unsigned short Wl[128 * 136];
  int tid = threadIdx.x;
  {
    int cg = (tid & 15) * 8;
    int r0 = tid >> 4;
#pragma unroll
    for (int i = 0; i < 8; ++i) {
      int row = r0 + i * 16;
      *reinterpret_cast<short8v*>(&Wl[row * 136 + cg]) =
          *reinterpret_cast<const short8v*>(Wb + row * D + cg);
    }
  }
  __syncthreads();
  int w = tid >> 6, lane = tid & 63;
  int lr = lane & 15, lg = lane >> 4;
#pragma unroll
  for (int rt = 0; rt < 2; ++rt) {
    int rbase = blockIdx.x * 128 + rt * 64 + w * 16;
    f32x4 acc[8];
#pragma unroll
    for (int j = 0; j < 8; ++j) acc[j] = f32x4{0.f, 0.f, 0.f, 0.f};
    // A fragment k = ks*32 + lg*8 -> slice ks, offset lg*8
    const unsigned short* abase = A + (size_t)(rbase + lr) * 32 + lg * 8;
#pragma unroll
    for (int ks = 0; ks < 4; ++ks) {
      short8v a = *reinterpret_cast<const short8v*>(abase + (size_t)ks * strideS);
#pragma unroll
      for (int jt = 0; jt < 8; ++jt) {
        short8v b = *reinterpret_cast<const short8v*>(&Wl[(jt * 16 + lr) * 136 + ks * 32 + lg * 8]);
        acc[jt] = __builtin_amdgcn_mfma_f32_16x16x32_bf16(a, b, acc[jt], 0, 0, 0);
      }
    }
    float vals[8][4];
    float ss[4] = {0.f, 0.f, 0.f, 0.f};
#pragma unroll
    for (int jt = 0; jt < 8; ++jt) {
      float bj = bias[jt * 16 + lr];
#pragma unroll
      for (int i = 0; i < 4; ++i) {
        float t = acc[jt][i] + bj;
        t = (t > 0.f) ? t : LEAKY * t;
        vals[jt][i] = t;
        ss[i] += t * t;
      }
    }
#pragma unroll
    for (int i = 0; i < 4; ++i) {
      float s = ss[i];
      s += __shfl_xor(s, 1); s += __shfl_xor(s, 2);
      s += __shfl_xor(s, 4); s += __shfl_xor(s, 8);
      ss[i] = 1.0f / fmaxf(sqrtf(s), 1e-12f);
    }
#pragma unroll
    for (int i = 0; i < 4; ++i) {
      int row = rbase + lg * 4 + i;
      if (row < n) {
#pragma unroll
        for (int jt = 0; jt < 8; ++jt) {  // out col j = jt*16+lr -> slice jt>>1, offset (jt&1)*16+lr
          enc[(size_t)(jt >> 1) * strideS + (size_t)row * 32 + (jt & 1) * 16 + lr] =
              (unsigned short)f2bf(vals[jt][i] * ss[i]);
        }
      }
    }
  }
}

// ---------------- gather + attention ----------------

__global__ void gather_tar(const unsigned short* __restrict__ src,
                           const int* __restrict__ poi_idx, float* __restrict__ tar,
                           int B, size_t strideS) {
  int j = blockIdx.x;
  if (j < B) {
    int t = threadIdx.x;  // 64 threads; features 2t, 2t+1
    int f = t * 2;
    size_t idx = (size_t)poi_idx[j];
    unsigned u = *reinterpret_cast<const unsigned*>(
        src + (size_t)(f >> 5) * strideS + idx * 32 + (f & 31));
    reinterpret_cast<float2*>(tar + (size_t)j * D)[t] = make_float2(bflo2f(u), bfhi2f(u));
  }
}

// qkv via MFMA with fused x_idx row gather from slice-major enc.
__global__ __launch_bounds__(256) void qkv_mfma(
    const unsigned short* __restrict__ enc, const int* __restrict__ x_idx,
    const unsigned short* __restrict__ Wb, const float* __restrict__ bias,
    float* __restrict__ qkv, int M, size_t strideS) {
  __shared__ unsigned short Wl[128 * 136];
  int tid = threadIdx.x;
  const unsigned short* Wslab = Wb + (size_t)blockIdx.y * 128 * D;
  {
    int cg = (tid & 15) * 8;
    int r0 = tid >> 4;
#pragma unroll
    for (int i = 0; i < 8; ++i) {
      int row = r0 + i * 16;
      *reinterpret_cast<short8v*>(&Wl[row * 136 + cg]) =
          *reinterpret_cast<const short8v*>(Wslab + row * D + cg);
    }
  }
  __syncthreads();
  int w = tid >> 6, lane = tid & 63;
  int lr = lane & 15, lg = lane >> 4;
  int colbase = blockIdx.y * 128;
#pragma unroll
  for (int rt = 0; rt < 2; ++rt) {
    int rbase = blockIdx.x * 128 + rt * 64 + w * 16;
    f32x4 acc[8];
#pragma unroll
    for (int j = 0; j < 8; ++j) acc[j] = f32x4{0.f, 0.f, 0.f, 0.f};
    const unsigned short* abase = enc + (size_t)x_idx[rbase + lr] * 32 + lg * 8;
#pragma unroll
    for (int ks = 0; ks < 4; ++ks) {
      short8v a = *reinterpret_cast<const short8v*>(abase + (size_t)ks * strideS);
#pragma unroll
      for (int jt = 0; jt < 8; ++jt) {
        short8v b = *reinterpret_cast<const short8v*>(&Wl[(jt * 16 + lr) * 136 + ks * 32 + lg * 8]);
        acc[jt] = __builtin_amdgcn_mfma_f32_16x16x32_bf16(a, b, acc[jt], 0, 0, 0);
      }
    }
#pragma unroll
    for (int jt = 0; jt < 8; ++jt) {
      int j = colbase + jt * 16 + lr;
      float bj = bias[j];
#pragma unroll
      for (int i = 0; i < 4; ++i) {
        int row = rbase + lg * 4 + i;
        if (row < M) qkv[(size_t)row * 384 + j] = acc[jt][i] + bj;
      }
    }
  }
}

__global__ __launch_bounds__(128) void attn_kernel(
    const float* __restrict__ qkv, float* __restrict__ o) {
  __shared__ float k_s[L_SEQ][HD];
  __shared__ float v_s[L_SEQ][HD];
  __shared__ float sc[L_SEQ][L_SEQ + 1];
  int b = blockIdx.x / HEADS;
  int h = blockIdx.x % HEADS;
  int tid = threadIdx.x;
  const size_t rowbase = (size_t)b * L_SEQ;
  for (int idx = tid; idx < L_SEQ * HD; idx += 128) {
    int l = idx >> 4, d2 = idx & 15;
    const float* base = qkv + (rowbase + l) * 384 + h * HD + d2;
    k_s[l][d2] = base[128];
    v_s[l][d2] = base[256];
  }
  __syncthreads();
  if (tid < L_SEQ) {
    float q[HD];
    const float* qp = qkv + (rowbase + tid) * 384 + h * HD;
#pragma unroll
    for (int d2 = 0; d2 < HD; ++d2) q[d2] = qp[d2];
    float m = -1e30f;
    for (int j = 0; j < L_SEQ; ++j) {
      float s = 0.f;
#pragma unroll
      for (int d2 = 0; d2 < HD; ++d2) s += q[d2] * k_s[j][d2];
      s *= 0.25f;
      sc[tid][j] = s;
      m = fmaxf(m, s);
    }
    float sum = 0.f;
    for (int j = 0; j < L_SEQ; ++j) {
      float e = expf(sc[tid][j] - m);
      sc[tid][j] = e;
      sum += e;
    }
    float inv = 1.f / sum;
    float oacc[HD];
#pragma unroll
    for (int d2 = 0; d2 < HD; ++d2) oacc[d2] = 0.f;
    for (int j = 0; j < L_SEQ; ++j) {
      float p = sc[tid][j];
#pragma unroll
      for (int d2 = 0; d2 < HD; ++d2) oacc[d2] += p * v_s[j][d2];
    }
    float* op = o + (rowbase + tid) * D + h * HD;
#pragma unroll
    for (int d2 = 0; d2 < HD; ++d2) op[d2] = oacc[d2] * inv;
  }
}

__global__ __launch_bounds__(128) void out_mean_kernel(
    const float* __restrict__ o, const float* __restrict__ Wo,
    const float* __restrict__ bo, float* __restrict__ out, int L) {
  __shared__ float m_s[D];
  int b = blockIdx.x, tid = threadIdx.x;
  float s = 0.f;
  for (int l = 0; l < L; ++l) s += o[((size_t)b * L + l) * D + tid];
  m_s[tid] = s / (float)L;
  __syncthreads();
  const float4* w4 = reinterpret_cast<const float4*>(Wo + (size_t)tid * D);
  float acc = 0.f;
  for (int k4 = 0; k4 < D / 4; ++k4) {
    float4 w = w4[k4];
    int k = k4 * 4;
    acc += m_s[k] * w.x + m_s[k + 1] * w.y + m_s[k + 2] * w.z + m_s[k + 3] * w.w;
  }
  out[(size_t)b * D + tid] = acc + bo[tid];
}

// ---------------- launch ----------------

extern "C" void kernel_launch(void* const* d_in, const int* in_sizes, int n_in,
                              void* d_out, int out_size, void* d_ws, size_t ws_size,
                              hipStream_t stream) {
  const float* embeds   = (const float*)d_in[0];
  const float* gcn_W    = (const float*)d_in[1];
  const float* gcn_b    = (const float*)d_in[2];
  const float* in_w     = (const float*)d_in[3];
  const float* in_b     = (const float*)d_in[4];
  const float* out_w    = (const float*)d_in[5];
  const float* out_b    = (const float*)d_in[6];
  const float* dist_vec = (const float*)d_in[7];
  const int*   edges    = (const int*)d_in[8];
  const int*   x_idx    = (const int*)d_in[9];
  const int*   poi_idx  = (const int*)d_in[10];
  float* out = (float*)d_out;

  int N  = in_sizes[0] / D;   // 50000
  int E  = in_sizes[7];       // 400000
  int BL = in_sizes[9];       // 6400
  int B  = in_sizes[10];      // 64
  int L  = BL / B;            // 100
  const int* e0 = edges;
  const int* e1 = edges + E;
  size_t total_edges = (size_t)2 * E + N;          // 850000
  int Npad = ((N + 127) / 128) * 128;              // 50048
  int NB   = (N + 1023) / 1024;                    // 49 (<= 64)
  size_t strideS = (size_t)Npad * 32;              // elements per 32-feature slice

  char* p = (char*)d_ws;
  auto alloc = [&](size_t bytes) { char* q = p; p += (bytes + 255) & ~(size_t)255; return q; };
  int*      deg     = (int*)alloc((size_t)N * 4);
  int*      row_ptr = (int*)alloc((size_t)(N + 1) * 4);
  int*      cursor  = (int*)alloc((size_t)N * 4);
  int*      bsum    = (int*)alloc((size_t)NB * 4);
  unsigned* ecw     = (unsigned*)alloc(total_edges * 4);
  unsigned short* emb_bf = (unsigned short*)alloc((size_t)Npad * D * 2);  // slice-major
  unsigned short* W_bf   = (unsigned short*)alloc((size_t)GCN_NUM * D * D * 2);
  unsigned short* inw_bf = (unsigned short*)alloc((size_t)3 * D * D * 2);
  unsigned short* agg_bf = (unsigned short*)alloc((size_t)Npad * D * 2);  // slice-major
  unsigned short* enc_bf = (unsigned short*)alloc((size_t)Npad * D * 2);  // slice-major
  float* qkv  = (float*)alloc((size_t)BL * 384 * 4);
  float* obuf = (float*)alloc((size_t)BL * D * 4);

  // fused converts + deg init
  int n4e = N * D / 4, n4w = GCN_NUM * D * D / 4, n4i = 3 * D * D / 4;
  int prep_tot = n4e + n4w + n4i + N;
  prep<<<(prep_tot + 255) / 256, 256, 0, stream>>>(
      embeds, emb_bf, n4e, gcn_W, W_bf, n4w, in_w, inw_bf, n4i, deg, N, strideS);

  // graph build
  count_deg<<<1024, 256, 0, stream>>>(e0, e1, deg, E);
  block_sum<<<NB, 1024, 0, stream>>>(deg, bsum, N);
  scan_final<<<NB, 1024, 0, stream>>>(deg, bsum, row_ptr, cursor, N, NB);
  int span = (N + SC_BUCKETS - 1) / SC_BUCKETS;
  int bpb = 512;
  scatter_edges_p<<<SC_BUCKETS * bpb, 256, 0, stream>>>(
      e0, e1, dist_vec, deg, cursor, ecw, E, N, span, bpb);

  // GCN layers (bf16 slice-major storage, sliced SpMM v2, MFMA dense)
  int spmm_grid = ((N + 15) / 16) * NSLICE;
  const unsigned short* cur_in = emb_bf;
  for (int i = 0; i < GCN_NUM; ++i) {
    spmm_s44<<<spmm_grid, 256, 0, stream>>>(row_ptr, ecw, cur_in, agg_bf, N, strideS);
    dense_mfma<<<Npad / 128, 256, 0, stream>>>(
        agg_bf, W_bf + (size_t)i * D * D, gcn_b + (size_t)i * D, enc_bf, N, strideS);
    cur_in = enc_bf;
  }

  // gathers + attention
  gather_tar<<<B, 64, 0, stream>>>(enc_bf, poi_idx, out + (size_t)B * D, B, strideS);
  dim3 qgrid(BL / 128, 3);
  qkv_mfma<<<qgrid, 256, 0, stream>>>(enc_bf, x_idx, inw_bf, in_b, qkv, BL, strideS);
  attn_kernel<<<B * HEADS, 128, 0, stream>>>(qkv, obuf);
  out_mean_kernel<<<B, 128, 0, stream>>>(obuf, out_w, out_b, out, L);
}